// Round 2
// baseline (231.098 us; speedup 1.0000x reference)
//
#include <hip/hip_runtime.h>
#include <math.h>

// SinkhornM round 4:
//  - Everything row-packed as f32x2 (lane = row index): MLP, tau, sigmoid,
//    Sinkhorn, epilogue -> v_pk_fma_f32 double-rate throughout.
//  - Margins folded into iteration matrices: B=a*rm (rows), C=a*cm (cols);
//    loop body is z=rcp(t); q=B^T z; w=rcp(q); t=C w  -- u/v multiplies
//    removed from the serial critical path; final t-update skipped.
//  - Weights as wave-uniform scalar (SGPR) broadcasts, streaming k-outer
//    layer fusion to keep VGPR pressure low.

#define QLOW  0.02f
#define QSPAN 0.96f
#define L2E   1.44269504088896f

typedef __attribute__((ext_vector_type(2))) float f32x2;

__device__ __forceinline__ float frcp(float x) { return __builtin_amdgcn_rcpf(x); }
__device__ __forceinline__ f32x2 pfma(f32x2 a, f32x2 b, f32x2 c) {
    return __builtin_elementwise_fma(a, b, c);
}
__device__ __forceinline__ f32x2 pmax0(f32x2 a) {
    const f32x2 z = {0.0f, 0.0f};
    return __builtin_elementwise_max(a, z);
}
__device__ __forceinline__ f32x2 prcp(f32x2 x) {
    f32x2 r; r.x = frcp(x.x); r.y = frcp(x.y); return r;
}
__device__ __forceinline__ f32x2 pexp2(f32x2 x) {
    f32x2 r; r.x = exp2f(x.x); r.y = exp2f(x.y); return r;
}
__device__ __forceinline__ f32x2 bc(float s) {
    f32x2 r; r.x = s; r.y = s; return r;
}

__global__ __launch_bounds__(256) void sinkhorn_fused(
    const float* __restrict__ margins,
    const float* __restrict__ W1, const float* __restrict__ b1,
    const float* __restrict__ W2, const float* __restrict__ b2,
    const float* __restrict__ W3, const float* __restrict__ b3,
    float* __restrict__ out, int n)
{
    const int tid  = blockIdx.x * blockDim.x + threadIdx.x;
    const int lane = tid & 63;
    const int base = (tid >> 6) * 128 + lane;   // rows: base, base+64
    const int r0 = base, r1 = base + 64;

    const float4* __restrict__ m4 = (const float4*)margins;
    const float4 a0A = m4[r0 * 2 + 0], a0B = m4[r0 * 2 + 1];
    const float4 a1A = m4[r1 * 2 + 0], a1B = m4[r1 * 2 + 1];

    // margins packed across the two rows: mp[k] = {row0[k], row1[k]}
    f32x2 mp[8];
    mp[0] = (f32x2){a0A.x, a1A.x}; mp[1] = (f32x2){a0A.y, a1A.y};
    mp[2] = (f32x2){a0A.z, a1A.z}; mp[3] = (f32x2){a0A.w, a1A.w};
    mp[4] = (f32x2){a0B.x, a1B.x}; mp[5] = (f32x2){a0B.y, a1B.y};
    mp[6] = (f32x2){a0B.z, a1B.z}; mp[7] = (f32x2){a0B.w, a1B.w};

    // ---- layers 1+2 fused, streaming over the 32 hidden units ----
    f32x2 h2p[16];
#pragma unroll
    for (int k = 0; k < 32; ++k) {
        f32x2 h = mp[0] * bc(W1[k]);                 // W1 is (8,32) row-major
#pragma unroll
        for (int kk = 1; kk < 8; ++kk)
            h = pfma(mp[kk], bc(W1[kk * 32 + k]), h);
        h = pmax0(h + bc(b1[k]));
        if (k == 0) {
#pragma unroll
            for (int j = 0; j < 16; ++j) h2p[j] = h * bc(W2[j]);
        } else {
#pragma unroll
            for (int j = 0; j < 16; ++j)
                h2p[j] = pfma(h, bc(W2[k * 16 + j]), h2p[j]);
        }
    }
#pragma unroll
    for (int j = 0; j < 16; ++j) h2p[j] = pmax0(h2p[j] + bc(b2[j]));

    // ---- layer 3: pp[9] ----
    f32x2 pp[9];
#pragma unroll
    for (int j = 0; j < 9; ++j) pp[j] = h2p[0] * bc(W3[j]);
#pragma unroll
    for (int k = 1; k < 16; ++k)
#pragma unroll
        for (int j = 0; j < 9; ++j)
            pp[j] = pfma(h2p[k], bc(W3[k * 9 + j]), pp[j]);
#pragma unroll
    for (int j = 0; j < 9; ++j) pp[j] = pp[j] + bc(b3[j]);

    // ---- tau in exp2/log2 space (packed) ----
    const f32x2 l0 = pp[0] * bc(L2E), l1 = pp[1] * bc(L2E);
    const f32x2 l2 = pp[2] * bc(L2E), l3 = pp[3] * bc(L2E);
    const f32x2 a00 = pexp2(l0), a01 = pexp2(l1);
    const f32x2 a10 = pexp2(l2), a11 = pexp2(l3);
    const f32x2 h01 = (l0 + l1) * bc(0.5f), h23 = (l2 + l3) * bc(0.5f);
    const f32x2 a02 = pexp2(h01);
    const f32x2 a12 = pexp2(h23);
    const f32x2 a20 = pexp2((l0 + l2) * bc(0.5f));
    const f32x2 a21 = pexp2((l1 + l3) * bc(0.5f));
    const f32x2 a22 = pexp2((h01 + h23) * bc(0.5f));

    // ---- squashed sigmoids (packed) ----
    const f32x2 one2 = {1.0f, 1.0f};
    const f32x2 s4 = pfma(bc(QSPAN), prcp(one2 + pexp2(pp[4] * bc(-L2E))), bc(QLOW));
    const f32x2 s5 = pfma(bc(QSPAN), prcp(one2 + pexp2(pp[5] * bc(-L2E))), bc(QLOW));
    const f32x2 s6 = pfma(bc(QSPAN), prcp(one2 + pexp2(pp[6] * bc(-L2E))), bc(QLOW));
    const f32x2 s7 = pfma(bc(QSPAN), prcp(one2 + pexp2(pp[7] * bc(-L2E))), bc(QLOW));

    const f32x2 M0 = mp[0], M1 = mp[1], M2 = mp[2];
    const f32x2 F0 = mp[3], F1 = mp[4], F2 = mp[5];

    const f32x2 rm0 = M0 * s4, rm1 = M1 * s5, rm2 = M2;
    const f32x2 cm0 = F0 * s6, cm1 = F1 * s7, cm2 = F2;
    const f32x2 um0 = pfma(-s4, M0, M0);
    const f32x2 um1 = pfma(-s5, M1, M1);
    const f32x2 uf0 = pfma(-s6, F0, F0);
    const f32x2 uf1 = pfma(-s7, F1, F1);

    // ---- folded Sinkhorn: B_ij = a_ij*rm_i, C_ij = a_ij*cm_j ----
    const f32x2 B00 = a00 * rm0, B01 = a01 * rm0, B02 = a02 * rm0;
    const f32x2 B10 = a10 * rm1, B11 = a11 * rm1, B12 = a12 * rm1;
    const f32x2 B20 = a20 * rm2, B21 = a21 * rm2, B22 = a22 * rm2;
    const f32x2 C00 = a00 * cm0, C01 = a01 * cm1, C02 = a02 * cm2;
    const f32x2 C10 = a10 * cm0, C11 = a11 * cm1, C12 = a12 * cm2;
    const f32x2 C20 = a20 * cm0, C21 = a21 * cm1, C22 = a22 * cm2;

    f32x2 t0 = (a00 + a01) + a02;
    f32x2 t1 = (a10 + a11) + a12;
    f32x2 t2 = (a20 + a21) + a22;
    f32x2 z0, z1, z2, w0, w1, w2;
#pragma unroll
    for (int it = 0; it < 10; ++it) {
        z0 = prcp(t0); z1 = prcp(t1); z2 = prcp(t2);
        const f32x2 q0 = pfma(B20, z2, pfma(B10, z1, B00 * z0));
        const f32x2 q1 = pfma(B21, z2, pfma(B11, z1, B01 * z0));
        const f32x2 q2 = pfma(B22, z2, pfma(B12, z1, B02 * z0));
        w0 = prcp(q0); w1 = prcp(q1); w2 = prcp(q2);
        if (it < 9) {
            t0 = pfma(C02, w2, pfma(C01, w1, C00 * w0));
            t1 = pfma(C12, w2, pfma(C11, w1, C10 * w0));
            t2 = pfma(C22, w2, pfma(C21, w1, C20 * w0));
        }
    }
    const f32x2 u0 = rm0 * z0, u1 = rm1 * z1, u2 = rm2 * z2;
    const f32x2 v0 = cm0 * w0, v1 = cm1 * w1, v2 = cm2 * w2;

    const f32x2 uv00 = u0 * v0, uv01 = u0 * v1, uv02 = u0 * v2;
    const f32x2 uv10 = u1 * v0, uv11 = u1 * v1, uv12 = u1 * v2;
    const f32x2 uv20 = u2 * v0, uv21 = u2 * v1, uv22 = u2 * v2;
    const f32x2 A00 = uv00 * a00, A01 = uv01 * a01, A02 = uv02 * a02;
    const f32x2 A10 = uv10 * a10, A11 = uv11 * a11, A12 = uv12 * a12;
    const f32x2 A20 = uv20 * a20, A21 = uv21 * a21, A22 = uv22 * a22;

    const f32x2 Vv = pexp2(pp[8] * bc(L2E));

    float4* __restrict__ o4 = (float4*)out;
    float* __restrict__ oV = out + (size_t)n * 16;

    o4[r0 * 4 + 0] = make_float4(A00.x, A01.x, A02.x, um0.x);
    o4[r0 * 4 + 1] = make_float4(A10.x, A11.x, A12.x, um1.x);
    o4[r0 * 4 + 2] = make_float4(A20.x, A21.x, A22.x, 0.0f);
    o4[r0 * 4 + 3] = make_float4(uf0.x, uf1.x, 0.0f, 0.0f);
    oV[r0] = Vv.x;

    o4[r1 * 4 + 0] = make_float4(A00.y, A01.y, A02.y, um0.y);
    o4[r1 * 4 + 1] = make_float4(A10.y, A11.y, A12.y, um1.y);
    o4[r1 * 4 + 2] = make_float4(A20.y, A21.y, A22.y, 0.0f);
    o4[r1 * 4 + 3] = make_float4(uf0.y, uf1.y, 0.0f, 0.0f);
    oV[r1] = Vv.y;
}

extern "C" void kernel_launch(void* const* d_in, const int* in_sizes, int n_in,
                              void* d_out, int out_size, void* d_ws, size_t ws_size,
                              hipStream_t stream) {
    const float* margins = (const float*)d_in[0];
    const float* W1 = (const float*)d_in[1];
    const float* b1 = (const float*)d_in[2];
    const float* W2 = (const float*)d_in[3];
    const float* b2 = (const float*)d_in[4];
    const float* W3 = (const float*)d_in[5];
    const float* b3 = (const float*)d_in[6];

    const int n = in_sizes[0] / 8;       // 1,048,576 rows
    const int threads = n / 2;           // 2 rows per thread
    dim3 block(256), grid(threads / 256);

    sinkhorn_fused<<<grid, block, 0, stream>>>(margins, W1, b1, W2, b2, W3, b3,
                                               (float*)d_out, n);
}

// Round 3
// 126.484 us; speedup vs baseline: 1.8271x; 1.8271x over previous
//
#include <hip/hip_runtime.h>
#include <math.h>

// SinkhornM round 5 = round-3 skeleton (proven 48us) + folded Sinkhorn tail.
//  - No LDS: weights as wave-uniform s_load/SGPR operands, j-outer order
//    (sequential weight addresses -> rolling SGPR window).
//  - MLP on f32x2 output pairs (unchanged from the 48us kernel).
//  - Tail per-row SEQUENTIAL (caps live set; round-4's all-rows-live
//    variant spilled to scratch and ran 5x slower).
//  - Folded Sinkhorn: B_ij=a_ij*rm_i, C_ij=a_ij*cm_j; body is
//    z=rcp(t); q=B^T z; w=rcp(q); t=C w. u/v multiplies off the critical
//    path; final t-update skipped. Math verified in round 4 (same absmax).

#define QLOW  0.02f
#define QSPAN 0.96f
#define L2E   1.44269504088896f

constexpr int R = 2;

typedef __attribute__((ext_vector_type(2))) float f32x2;

__device__ __forceinline__ float frcp(float x) { return __builtin_amdgcn_rcpf(x); }
__device__ __forceinline__ f32x2 pfma(f32x2 a, f32x2 b, f32x2 c) {
    return __builtin_elementwise_fma(a, b, c);
}

__global__ __launch_bounds__(256) void sinkhorn_fused(
    const float* __restrict__ margins,
    const float* __restrict__ W1, const float* __restrict__ b1,
    const float* __restrict__ W2, const float* __restrict__ b2,
    const float* __restrict__ W3, const float* __restrict__ b3,
    float* __restrict__ out, int n)
{
    const int tid  = blockIdx.x * blockDim.x + threadIdx.x;
    const int lane = tid & 63;
    const int base = (tid >> 6) * (64 * R) + lane;  // rows base, base+64

    const float4* __restrict__ m4 = (const float4*)margins;

    float m[R][8];
#pragma unroll
    for (int r = 0; r < R; ++r) {
        const int row = base + 64 * r;
        const float4 a0 = m4[row * 2 + 0];
        const float4 a1 = m4[row * 2 + 1];
        m[r][0] = a0.x; m[r][1] = a0.y; m[r][2] = a0.z; m[r][3] = a0.w;
        m[r][4] = a1.x; m[r][5] = a1.y; m[r][6] = a1.z; m[r][7] = a1.w;
    }

    const f32x2* __restrict__ W1v = (const f32x2*)W1;  // (8,32) -> [k][16 pairs]
    const f32x2* __restrict__ W2v = (const f32x2*)W2;  // (32,16) -> [k][8 pairs]
    const f32x2* __restrict__ b1v = (const f32x2*)b1;
    const f32x2* __restrict__ b2v = (const f32x2*)b2;

    // ---- layer 1: h1 = relu(m @ W1 + b1), 32 wide = 16 pairs ----
    f32x2 h1[R][16];
#pragma unroll
    for (int j = 0; j < 16; ++j) {
        const f32x2 bb = b1v[j];
#pragma unroll
        for (int r = 0; r < R; ++r) h1[r][j] = bb;
    }
#pragma unroll
    for (int k = 0; k < 8; ++k) {
        f32x2 mk[R];
#pragma unroll
        for (int r = 0; r < R; ++r) { mk[r].x = m[r][k]; mk[r].y = m[r][k]; }
#pragma unroll
        for (int j = 0; j < 16; ++j) {
            const f32x2 w = W1v[k * 16 + j];
#pragma unroll
            for (int r = 0; r < R; ++r) h1[r][j] = pfma(mk[r], w, h1[r][j]);
        }
    }
    const f32x2 zero2 = {0.0f, 0.0f};
#pragma unroll
    for (int j = 0; j < 16; ++j)
#pragma unroll
        for (int r = 0; r < R; ++r)
            h1[r][j] = __builtin_elementwise_max(h1[r][j], zero2);

    // ---- layer 2: h2 = relu(h1 @ W2 + b2), 16 wide = 8 pairs ----
    f32x2 h2[R][8];
#pragma unroll
    for (int j = 0; j < 8; ++j) {
        const f32x2 bb = b2v[j];
#pragma unroll
        for (int r = 0; r < R; ++r) h2[r][j] = bb;
    }
#pragma unroll
    for (int k = 0; k < 32; ++k) {
        f32x2 hk[R];
#pragma unroll
        for (int r = 0; r < R; ++r) {
            const float s = (k & 1) ? h1[r][k >> 1].y : h1[r][k >> 1].x;
            hk[r].x = s; hk[r].y = s;
        }
#pragma unroll
        for (int j = 0; j < 8; ++j) {
            const f32x2 w = W2v[k * 8 + j];
#pragma unroll
            for (int r = 0; r < R; ++r) h2[r][j] = pfma(hk[r], w, h2[r][j]);
        }
    }
#pragma unroll
    for (int j = 0; j < 8; ++j)
#pragma unroll
        for (int r = 0; r < R; ++r)
            h2[r][j] = __builtin_elementwise_max(h2[r][j], zero2);

    // ---- layer 3: p = h2 @ W3 + b3, 9 wide = 4 pairs + 1 scalar ----
    f32x2 p01[R], p23[R], p45[R], p67[R];
    float p8[R];
    {
        const f32x2 b01 = {b3[0], b3[1]};
        const f32x2 b23 = {b3[2], b3[3]};
        const f32x2 b45 = {b3[4], b3[5]};
        const f32x2 b67 = {b3[6], b3[7]};
        const float b8  = b3[8];
#pragma unroll
        for (int r = 0; r < R; ++r) {
            p01[r] = b01; p23[r] = b23; p45[r] = b45; p67[r] = b67; p8[r] = b8;
        }
    }
#pragma unroll
    for (int k = 0; k < 16; ++k) {
        const f32x2 w01 = {W3[k * 9 + 0], W3[k * 9 + 1]};
        const f32x2 w23 = {W3[k * 9 + 2], W3[k * 9 + 3]};
        const f32x2 w45 = {W3[k * 9 + 4], W3[k * 9 + 5]};
        const f32x2 w67 = {W3[k * 9 + 6], W3[k * 9 + 7]};
        const float w8  = W3[k * 9 + 8];
#pragma unroll
        for (int r = 0; r < R; ++r) {
            const float s = (k & 1) ? h2[r][k >> 1].y : h2[r][k >> 1].x;
            f32x2 hb; hb.x = s; hb.y = s;
            p01[r] = pfma(hb, w01, p01[r]);
            p23[r] = pfma(hb, w23, p23[r]);
            p45[r] = pfma(hb, w45, p45[r]);
            p67[r] = pfma(hb, w67, p67[r]);
            p8[r]  = fmaf(s, w8, p8[r]);
        }
    }

    float4* __restrict__ o4 = (float4*)out;
    float* __restrict__ oV = out + (size_t)n * 16;

#pragma unroll
    for (int r = 0; r < R; ++r) {
        const int row = base + 64 * r;

        const float l0 = p01[r].x * L2E, l1 = p01[r].y * L2E;
        const float l2 = p23[r].x * L2E, l3 = p23[r].y * L2E;

        const float a00 = exp2f(l0), a01 = exp2f(l1);
        const float a10 = exp2f(l2), a11 = exp2f(l3);
        const float h01 = (l0 + l1) * 0.5f, h23 = (l2 + l3) * 0.5f;
        const float a02 = exp2f(h01);
        const float a12 = exp2f(h23);
        const float a20 = exp2f((l0 + l2) * 0.5f);
        const float a21 = exp2f((l1 + l3) * 0.5f);
        const float a22 = exp2f((h01 + h23) * 0.5f);

        const float s4 = fmaf(QSPAN, frcp(1.0f + exp2f(-L2E * p45[r].x)), QLOW);
        const float s5 = fmaf(QSPAN, frcp(1.0f + exp2f(-L2E * p45[r].y)), QLOW);
        const float s6 = fmaf(QSPAN, frcp(1.0f + exp2f(-L2E * p67[r].x)), QLOW);
        const float s7 = fmaf(QSPAN, frcp(1.0f + exp2f(-L2E * p67[r].y)), QLOW);

        const float M0 = m[r][0], M1 = m[r][1], M2 = m[r][2];
        const float F0 = m[r][3], F1 = m[r][4], F2 = m[r][5];

        const float rm0 = M0 * s4, rm1 = M1 * s5, rm2 = M2;
        const float cm0 = F0 * s6, cm1 = F1 * s7, cm2 = F2;
        const float um0 = fmaf(-s4, M0, M0);
        const float um1 = fmaf(-s5, M1, M1);
        const float uf0 = fmaf(-s6, F0, F0);
        const float uf1 = fmaf(-s7, F1, F1);

        // folded iteration matrices: B_ij = a_ij*rm_i, C_ij = a_ij*cm_j
        const float B00 = a00 * rm0, B01 = a01 * rm0, B02 = a02 * rm0;
        const float B10 = a10 * rm1, B11 = a11 * rm1, B12 = a12 * rm1;
        const float B20 = a20 * rm2, B21 = a21 * rm2, B22 = a22 * rm2;
        const float C00 = a00 * cm0, C01 = a01 * cm1, C02 = a02 * cm2;
        const float C10 = a10 * cm0, C11 = a11 * cm1, C12 = a12 * cm2;
        const float C20 = a20 * cm0, C21 = a21 * cm1, C22 = a22 * cm2;

        float t0 = (a00 + a01) + a02;   // A @ v with v = 1
        float t1 = (a10 + a11) + a12;
        float t2 = (a20 + a21) + a22;
        float z0, z1, z2, w0, w1, w2;
#pragma unroll
        for (int it = 0; it < 10; ++it) {
            z0 = frcp(t0); z1 = frcp(t1); z2 = frcp(t2);
            const float q0 = fmaf(B20, z2, fmaf(B10, z1, B00 * z0));
            const float q1 = fmaf(B21, z2, fmaf(B11, z1, B01 * z0));
            const float q2 = fmaf(B22, z2, fmaf(B12, z1, B02 * z0));
            w0 = frcp(q0); w1 = frcp(q1); w2 = frcp(q2);
            if (it < 9) {
                t0 = fmaf(C02, w2, fmaf(C01, w1, C00 * w0));
                t1 = fmaf(C12, w2, fmaf(C11, w1, C10 * w0));
                t2 = fmaf(C22, w2, fmaf(C21, w1, C20 * w0));
            }
        }
        const float u0 = rm0 * z0, u1 = rm1 * z1, u2 = rm2 * z2;
        const float v0 = cm0 * w0, v1 = cm1 * w1, v2 = cm2 * w2;

        const float A0f = u0 * a00 * v0, A1f = u0 * a01 * v1, A2f = u0 * a02 * v2;
        const float A3f = u1 * a10 * v0, A4f = u1 * a11 * v1, A5f = u1 * a12 * v2;
        const float A6f = u2 * a20 * v0, A7f = u2 * a21 * v1, A8f = u2 * a22 * v2;

        o4[row * 4 + 0] = make_float4(A0f, A1f, A2f, um0);
        o4[row * 4 + 1] = make_float4(A3f, A4f, A5f, um1);
        o4[row * 4 + 2] = make_float4(A6f, A7f, A8f, 0.0f);
        o4[row * 4 + 3] = make_float4(uf0, uf1, 0.0f, 0.0f);
        oV[row] = exp2f(p8[r] * L2E);
    }
}

extern "C" void kernel_launch(void* const* d_in, const int* in_sizes, int n_in,
                              void* d_out, int out_size, void* d_ws, size_t ws_size,
                              hipStream_t stream) {
    const float* margins = (const float*)d_in[0];
    const float* W1 = (const float*)d_in[1];
    const float* b1 = (const float*)d_in[2];
    const float* W2 = (const float*)d_in[3];
    const float* b2 = (const float*)d_in[4];
    const float* W3 = (const float*)d_in[5];
    const float* b3 = (const float*)d_in[6];

    const int n = in_sizes[0] / 8;       // 1,048,576 rows
    const int threads = n / R;
    dim3 block(256), grid(threads / 256);

    sinkhorn_fused<<<grid, block, 0, stream>>>(margins, W1, b1, W2, b2, W3, b3,
                                               (float*)d_out, n);
}